// Round 1
// baseline (33.508 us; speedup 1.0000x reference)
//
#include <hip/hip_runtime.h>
#include <hip/hip_bf16.h>

#define BB 2
#define CC 512
#define TT 1024
#define WIN 32
#define LL 33   // WIN+1

typedef __attribute__((ext_vector_type(8))) short short8;
typedef __attribute__((ext_vector_type(4))) float f32x4;

// ---------------------------------------------------------------------------
// Kernel 1: fused depthwise causal conv (KSZ=3) + per-channel local softmax
// attention.  One block per (b,c) row.  attn written as bf16 (B,C,T).
// ---------------------------------------------------------------------------
__global__ __launch_bounds__(256) void conv_attn_kernel(
    const float* __restrict__ qin, const float* __restrict__ kin,
    const float* __restrict__ vin, const int* __restrict__ mask,
    const float* __restrict__ wq, const float* __restrict__ wk,
    const float* __restrict__ wv, __hip_bfloat16* __restrict__ attn)
{
    const int blk = blockIdx.x;
    const int b = blk >> 9;          // / CC
    const int c = blk & (CC - 1);
    const int tid = threadIdx.x;

    __shared__ float k_s[WIN + TT];  // conv'd k, index p+WIN (p<0 region = 0)
    __shared__ float v_s[WIN + TT];  // conv'd v
    __shared__ float m_s[TT];        // mask row as float

    const float wq0 = wq[c*3+0], wq1 = wq[c*3+1], wq2 = wq[c*3+2];
    const float wk0 = wk[c*3+0], wk1 = wk[c*3+1], wk2 = wk[c*3+2];
    const float wv0 = wv[c*3+0], wv1 = wv[c*3+1], wv2 = wv[c*3+2];

    const float* qrow = qin + ((size_t)b * CC + c) * TT;
    const float* krow = kin + ((size_t)b * CC + c) * TT;
    const float* vrow = vin + ((size_t)b * CC + c) * TT;
    const int*   mrow = mask + (size_t)b * TT;

    for (int i = tid; i < WIN; i += 256) { k_s[i] = 0.f; v_s[i] = 0.f; }
    for (int p = tid; p < TT; p += 256) {
        // causal conv: y[p] = w0*x[p-2] + w1*x[p-1] + w2*x[p]
        float km2 = (p >= 2) ? krow[p-2] : 0.f;
        float km1 = (p >= 1) ? krow[p-1] : 0.f;
        float k0  = krow[p];
        k_s[WIN + p] = fmaf(wk0, km2, fmaf(wk1, km1, wk2 * k0));
        float vm2 = (p >= 2) ? vrow[p-2] : 0.f;
        float vm1 = (p >= 1) ? vrow[p-1] : 0.f;
        float v0  = vrow[p];
        v_s[WIN + p] = fmaf(wv0, vm2, fmaf(wv1, vm1, wv2 * v0));
        m_s[p] = (float)mrow[p];
    }
    __syncthreads();

    #pragma unroll
    for (int rep = 0; rep < TT / 256; ++rep) {
        const int t = tid + rep * 256;
        float qm2 = (t >= 2) ? qrow[t-2] : 0.f;
        float qm1 = (t >= 1) ? qrow[t-1] : 0.f;
        float q0  = qrow[t];
        const float qs = fmaf(wq0, qm2, fmaf(wq1, qm1, wq2 * q0)) * 0.125f; // /SCALE

        float s[LL];
        float mx = -1e9f;
        #pragma unroll
        for (int l = 0; l < LL; ++l) {
            int p = t - WIN + l;          // key position
            int pc = p < 0 ? 0 : p;
            bool valid = (p >= 0) && (m_s[pc] != 0.f);
            s[l] = valid ? qs * k_s[t + l] : -1e9f;
            mx = fmaxf(mx, s[l]);
        }
        float sum = 0.f, acc = 0.f;
        #pragma unroll
        for (int l = 0; l < LL; ++l) {
            float e = __expf(s[l] - mx);
            sum += e;
            acc = fmaf(e, v_s[t + l], acc);   // v_s pad region is 0 == v_unf pad
        }
        attn[((size_t)b * CC + c) * TT + t] = __float2bfloat16(acc / sum);
    }
}

// ---------------------------------------------------------------------------
// Kernel 2: out[b,o,t] = sum_c w_fc[o,c] * attn[b,c,t] + b_fc[o]
// bf16 MFMA 16x16x32, 64x64 tile, 4 waves (2x2), BK=32.
// ---------------------------------------------------------------------------
#define BM 64
#define BN 64
#define BK 32
#define LDP 40   // padded row length (bf16 elems), 80B rows, 16B-aligned

__global__ __launch_bounds__(256) void fc_gemm_kernel(
    const __hip_bfloat16* __restrict__ attn,  // (B, C, T) bf16
    const float* __restrict__ wfc,            // (512, 512) row-major (o, c)
    const float* __restrict__ bfc,            // (512,)
    float* __restrict__ out)                  // (B, 512, T) f32
{
    const int t0 = blockIdx.x * BN;
    const int o0 = blockIdx.y * BM;
    const int b  = blockIdx.z;
    const int tid  = threadIdx.x;
    const int lane = tid & 63;
    const int wave = tid >> 6;
    const int wr = wave >> 1;      // wave row (o)   0..1
    const int wc = wave & 1;       // wave col (t)   0..1
    const int fr = lane & 15;      // fragment row/col index
    const int fh = lane >> 4;      // k-half selector 0..3

    __shared__ alignas(16) __hip_bfloat16 a_lds[BM][LDP];  // [o][k]
    __shared__ alignas(16) __hip_bfloat16 b_lds[BN][LDP];  // [t][k]

    f32x4 acc[2][2] = {};

    // A staging indices: thread -> (row of A, k-offset)
    const int ar = tid >> 2;             // 0..63
    const int ak = (tid & 3) * 8;        // 0,8,16,24
    // B staging indices: thread -> (t row, k-offset); global reads coalesced in t
    const int brow = tid & 63;           // 0..63
    const int bkc  = (tid >> 6) * 8;     // 0,8,16,24

    for (int k0 = 0; k0 < CC; k0 += BK) {
        __syncthreads();
        // --- stage A: w_fc f32 -> bf16 ---
        {
            const float* ap = wfc + (size_t)(o0 + ar) * CC + k0 + ak;
            float4 a01 = *reinterpret_cast<const float4*>(ap);
            float4 a23 = *reinterpret_cast<const float4*>(ap + 4);
            union { short8 v; __hip_bfloat16 h[8]; } pk;
            pk.h[0] = __float2bfloat16(a01.x); pk.h[1] = __float2bfloat16(a01.y);
            pk.h[2] = __float2bfloat16(a01.z); pk.h[3] = __float2bfloat16(a01.w);
            pk.h[4] = __float2bfloat16(a23.x); pk.h[5] = __float2bfloat16(a23.y);
            pk.h[6] = __float2bfloat16(a23.z); pk.h[7] = __float2bfloat16(a23.w);
            *reinterpret_cast<short8*>(&a_lds[ar][ak]) = pk.v;
        }
        // --- stage B: attn bf16, transpose (c,t) -> [t][k] in LDS ---
        {
            const __hip_bfloat16* bp =
                attn + ((size_t)b * CC + k0 + bkc) * TT + t0 + brow;
            union { short8 v; __hip_bfloat16 h[8]; } pb;
            #pragma unroll
            for (int j = 0; j < 8; ++j) pb.h[j] = bp[(size_t)j * TT];
            *reinterpret_cast<short8*>(&b_lds[brow][bkc]) = pb.v;
        }
        __syncthreads();

        short8 afrag[2], bfrag[2];
        #pragma unroll
        for (int i = 0; i < 2; ++i) {
            afrag[i] = *reinterpret_cast<const short8*>(&a_lds[wr*32 + i*16 + fr][fh*8]);
            bfrag[i] = *reinterpret_cast<const short8*>(&b_lds[wc*32 + i*16 + fr][fh*8]);
        }
        #pragma unroll
        for (int i = 0; i < 2; ++i)
            #pragma unroll
            for (int j = 0; j < 2; ++j)
                acc[i][j] = __builtin_amdgcn_mfma_f32_16x16x32_bf16(
                    afrag[i], bfrag[j], acc[i][j], 0, 0, 0);
    }

    // epilogue: D row=(lane>>4)*4+r, col=lane&15
    #pragma unroll
    for (int i = 0; i < 2; ++i) {
        #pragma unroll
        for (int j = 0; j < 2; ++j) {
            const int tcol = t0 + wc*32 + j*16 + fr;
            #pragma unroll
            for (int r = 0; r < 4; ++r) {
                const int o = o0 + wr*32 + i*16 + fh*4 + r;
                out[((size_t)b * CC + o) * TT + tcol] = acc[i][j][r] + bfc[o];
            }
        }
    }
}

// ---------------------------------------------------------------------------
// Kernel 3: rt_mask output (int mask -> float values, concatenated after out0)
// ---------------------------------------------------------------------------
__global__ void mask_out_kernel(const int* __restrict__ mask,
                                float* __restrict__ out)
{
    int i = blockIdx.x * blockDim.x + threadIdx.x;
    if (i < BB * TT) out[i] = (float)mask[i];
}

extern "C" void kernel_launch(void* const* d_in, const int* in_sizes, int n_in,
                              void* d_out, int out_size, void* d_ws, size_t ws_size,
                              hipStream_t stream) {
    const float* qin  = (const float*)d_in[0];
    const float* kin  = (const float*)d_in[1];
    const float* vin  = (const float*)d_in[2];
    const int*   mask = (const int*)  d_in[3];
    const float* wq   = (const float*)d_in[4];
    const float* wk   = (const float*)d_in[5];
    const float* wv   = (const float*)d_in[6];
    const float* wfc  = (const float*)d_in[7];
    const float* bfc  = (const float*)d_in[8];
    float* out = (float*)d_out;
    __hip_bfloat16* attn = (__hip_bfloat16*)d_ws;   // 2 MB bf16 scratch

    conv_attn_kernel<<<BB * CC, 256, 0, stream>>>(qin, kin, vin, mask,
                                                  wq, wk, wv, attn);
    dim3 g(TT / BN, CC / BM, BB);   // (16, 8, 2)
    fc_gemm_kernel<<<g, 256, 0, stream>>>(attn, wfc, bfc, out);
    mask_out_kernel<<<(BB * TT + 255) / 256, 256, 0, stream>>>(
        mask, out + (size_t)BB * CC * TT);
}

// Round 2
// 22.104 us; speedup vs baseline: 1.5159x; 1.5159x over previous
//
#include <hip/hip_runtime.h>
#include <hip/hip_bf16.h>

#define BB 2
#define CC 512
#define TT 1024
#define WIN 32
#define LL 33   // WIN+1

typedef __attribute__((ext_vector_type(8))) short short8;
typedef __attribute__((ext_vector_type(4))) short short4v;
typedef __attribute__((ext_vector_type(4))) float f32x4;

#if __has_builtin(__builtin_amdgcn_exp2f)
#define EXP2(x) __builtin_amdgcn_exp2f(x)
#else
#define EXP2(x) exp2f(x)
#endif

// (1/SCALE) * log2(e)  with SCALE = sqrt(64) = 8
#define QSCALE 0.18033688011112042f

// ---------------------------------------------------------------------------
// Kernel 1 (fused): blocks [0, BB*CC)        -> conv + local softmax attention
//                   blocks [BB*CC, +256)     -> pack w_fc f32 -> bf16
//                   block  [BB*CC+256]       -> mask float output
// ---------------------------------------------------------------------------
__global__ __launch_bounds__(256) void fused_conv_attn_kernel(
    const float* __restrict__ qin, const float* __restrict__ kin,
    const float* __restrict__ vin, const int* __restrict__ mask,
    const float* __restrict__ wq, const float* __restrict__ wk,
    const float* __restrict__ wv, const float* __restrict__ wfc,
    __hip_bfloat16* __restrict__ attn, __hip_bfloat16* __restrict__ wpack,
    float* __restrict__ mout)
{
    const int blk = blockIdx.x;
    const int tid = threadIdx.x;

    if (blk >= BB * CC) {
        const int xb = blk - BB * CC;
        if (xb < 256) {
            // pack w_fc -> bf16 (262144 elems, 4 per thread)
            const int base = (xb * 256 + tid) * 4;
            float4 w = *reinterpret_cast<const float4*>(wfc + base);
            union { short4v s; __hip_bfloat16 h[4]; } o;
            o.h[0] = __float2bfloat16(w.x); o.h[1] = __float2bfloat16(w.y);
            o.h[2] = __float2bfloat16(w.z); o.h[3] = __float2bfloat16(w.w);
            *reinterpret_cast<short4v*>(&wpack[base]) = o.s;
        } else {
            for (int j = tid; j < BB * TT; j += 256) mout[j] = (float)mask[j];
        }
        return;
    }

    const int b = blk >> 9;          // / CC
    const int c = blk & (CC - 1);

    __shared__ alignas(16) float k_s[WIN + TT];  // conv'd k at index p+WIN, front pad 0
    __shared__ alignas(16) float v_s[WIN + TT];
    __shared__ alignas(16) float m_s[WIN + TT];  // mask as float, front pad 0

    const float wq0 = wq[c*3+0], wq1 = wq[c*3+1], wq2 = wq[c*3+2];
    const float wk0 = wk[c*3+0], wk1 = wk[c*3+1], wk2 = wk[c*3+2];
    const float wv0 = wv[c*3+0], wv1 = wv[c*3+1], wv2 = wv[c*3+2];

    const float* qrow = qin + ((size_t)b * CC + c) * TT;
    const float* krow = kin + ((size_t)b * CC + c) * TT;
    const float* vrow = vin + ((size_t)b * CC + c) * TT;
    const int*   mrow = mask + (size_t)b * TT;

    const int p0 = tid * 4;

    // ---- stage conv'd k, v and mask into LDS (vectorized) ----
    {
        float4 kx = *reinterpret_cast<const float4*>(krow + p0);
        float km1 = (p0 >= 1) ? krow[p0-1] : 0.f;
        float km2 = (p0 >= 2) ? krow[p0-2] : 0.f;
        float4 ky;
        ky.x = fmaf(wk0, km2,  fmaf(wk1, km1,  wk2*kx.x));
        ky.y = fmaf(wk0, km1,  fmaf(wk1, kx.x, wk2*kx.y));
        ky.z = fmaf(wk0, kx.x, fmaf(wk1, kx.y, wk2*kx.z));
        ky.w = fmaf(wk0, kx.y, fmaf(wk1, kx.z, wk2*kx.w));
        *reinterpret_cast<float4*>(&k_s[WIN + p0]) = ky;

        float4 vx = *reinterpret_cast<const float4*>(vrow + p0);
        float vm1 = (p0 >= 1) ? vrow[p0-1] : 0.f;
        float vm2 = (p0 >= 2) ? vrow[p0-2] : 0.f;
        float4 vy;
        vy.x = fmaf(wv0, vm2,  fmaf(wv1, vm1,  wv2*vx.x));
        vy.y = fmaf(wv0, vm1,  fmaf(wv1, vx.x, wv2*vx.y));
        vy.z = fmaf(wv0, vx.x, fmaf(wv1, vx.y, wv2*vx.z));
        vy.w = fmaf(wv0, vx.y, fmaf(wv1, vx.z, wv2*vx.w));
        *reinterpret_cast<float4*>(&v_s[WIN + p0]) = vy;

        int4 mi = *reinterpret_cast<const int4*>(mrow + p0);
        float4 mf;
        mf.x = (float)mi.x; mf.y = (float)mi.y; mf.z = (float)mi.z; mf.w = (float)mi.w;
        *reinterpret_cast<float4*>(&m_s[WIN + p0]) = mf;

        if (tid < WIN) { k_s[tid] = 0.f; v_s[tid] = 0.f; m_s[tid] = 0.f; }
    }

    // ---- q conv for this thread's 4 consecutive t's (registers only) ----
    float qsv[4];
    {
        float4 qx = *reinterpret_cast<const float4*>(qrow + p0);
        float qm1 = (p0 >= 1) ? qrow[p0-1] : 0.f;
        float qm2 = (p0 >= 2) ? qrow[p0-2] : 0.f;
        qsv[0] = fmaf(wq0, qm2,  fmaf(wq1, qm1,  wq2*qx.x)) * QSCALE;
        qsv[1] = fmaf(wq0, qm1,  fmaf(wq1, qx.x, wq2*qx.y)) * QSCALE;
        qsv[2] = fmaf(wq0, qx.x, fmaf(wq1, qx.y, wq2*qx.z)) * QSCALE;
        qsv[3] = fmaf(wq0, qx.y, fmaf(wq1, qx.z, wq2*qx.w)) * QSCALE;
    }

    __syncthreads();

    // ---- load 36-wide register windows (9 aligned b128 reads per array) ----
    float kk[36], vv[36], mm[36];
    #pragma unroll
    for (int j = 0; j < 9; ++j) {
        float4 t4 = *reinterpret_cast<const float4*>(&k_s[p0 + 4*j]);
        kk[4*j] = t4.x; kk[4*j+1] = t4.y; kk[4*j+2] = t4.z; kk[4*j+3] = t4.w;
        float4 u4 = *reinterpret_cast<const float4*>(&v_s[p0 + 4*j]);
        vv[4*j] = u4.x; vv[4*j+1] = u4.y; vv[4*j+2] = u4.z; vv[4*j+3] = u4.w;
        float4 w4 = *reinterpret_cast<const float4*>(&m_s[p0 + 4*j]);
        mm[4*j] = w4.x; mm[4*j+1] = w4.y; mm[4*j+2] = w4.z; mm[4*j+3] = w4.w;
    }

    // ---- 4 t's, 33-wide softmax-weighted sum, no max pass (scores tiny) ----
    union { short4v s; __hip_bfloat16 h[4]; } ob;
    #pragma unroll
    for (int dt = 0; dt < 4; ++dt) {
        const float qs = qsv[dt];
        float sum = 0.f, acc = 0.f;
        #pragma unroll
        for (int l = 0; l < LL; ++l) {
            float em = EXP2(qs * kk[dt + l]) * mm[dt + l];
            sum += em;
            acc = fmaf(em, vv[dt + l], acc);
        }
        ob.h[dt] = __float2bfloat16(acc * __builtin_amdgcn_rcpf(sum));
    }
    *reinterpret_cast<short4v*>(&attn[((size_t)b * CC + c) * TT + p0]) = ob.s;
}

// ---------------------------------------------------------------------------
// Kernel 2: out[b,o,t] = sum_c wpack[o,c] * attn[b,c,t] + b_fc[o]
// bf16 MFMA 16x16x32, 64(o) x 32(t) tile, BK=64, double-buffered LDS.
// ---------------------------------------------------------------------------
#define BM2 64
#define BN2 32
#define BK2 64
#define LDP2 72   // padded row (bf16), 144B rows -> 2-way (free) LDS aliasing

__global__ __launch_bounds__(256) void fc_gemm_kernel(
    const __hip_bfloat16* __restrict__ attn,   // (B, C, T) bf16
    const __hip_bfloat16* __restrict__ wpack,  // (512, 512) bf16 (o, c)
    const float* __restrict__ bfc,             // (512,)
    float* __restrict__ out)                   // (B, 512, T) f32
{
    const int t0 = blockIdx.x * BN2;
    const int o0 = blockIdx.y * BM2;
    const int b  = blockIdx.z;
    const int tid  = threadIdx.x;
    const int lane = tid & 63;
    const int wave = tid >> 6;
    const int wr = wave >> 1;      // o half   0..1
    const int wc = wave & 1;       // t half   0..1
    const int fr = lane & 15;
    const int fh = lane >> 4;

    __shared__ alignas(16) __hip_bfloat16 a_lds[2][BM2][LDP2];  // [o][k]
    __shared__ alignas(16) __hip_bfloat16 b_lds[2][BN2][LDP2];  // [t][k]

    f32x4 acc[2] = {};

    const int ar = tid >> 2;             // A row 0..63
    const int ak = (tid & 3) * 16;       // A k-offset 0,16,32,48
    const int br = tid & 31;             // B t-row 0..31
    const int bk = (tid >> 5) * 8;       // B k-offset 0..56

    short8 areg0, areg1;
    union { short8 v; __hip_bfloat16 h[8]; } breg;

    const __hip_bfloat16* aptr = wpack + (size_t)(o0 + ar) * CC + ak;
    const __hip_bfloat16* bptr = attn + ((size_t)b * CC + bk) * TT + t0 + br;

    // prologue: stage k0 = 0
    areg0 = *reinterpret_cast<const short8*>(aptr);
    areg1 = *reinterpret_cast<const short8*>(aptr + 8);
    #pragma unroll
    for (int j = 0; j < 8; ++j) breg.h[j] = bptr[(size_t)j * TT];
    *reinterpret_cast<short8*>(&a_lds[0][ar][ak])     = areg0;
    *reinterpret_cast<short8*>(&a_lds[0][ar][ak + 8]) = areg1;
    *reinterpret_cast<short8*>(&b_lds[0][br][bk])     = breg.v;
    __syncthreads();

    #pragma unroll
    for (int it = 0; it < CC / BK2; ++it) {   // 8 iterations
        const int cur = it & 1;
        if (it < CC / BK2 - 1) {
            const int k1 = (it + 1) * BK2;
            areg0 = *reinterpret_cast<const short8*>(aptr + k1);
            areg1 = *reinterpret_cast<const short8*>(aptr + k1 + 8);
            #pragma unroll
            for (int j = 0; j < 8; ++j) breg.h[j] = bptr[(size_t)(k1 + j) * TT];
        }
        short8 af[2][2], bf[2];
        #pragma unroll
        for (int i = 0; i < 2; ++i)
            #pragma unroll
            for (int ks = 0; ks < 2; ++ks)
                af[i][ks] = *reinterpret_cast<const short8*>(
                    &a_lds[cur][wr*32 + i*16 + fr][ks*32 + fh*8]);
        #pragma unroll
        for (int ks = 0; ks < 2; ++ks)
            bf[ks] = *reinterpret_cast<const short8*>(
                &b_lds[cur][wc*16 + fr][ks*32 + fh*8]);
        #pragma unroll
        for (int ks = 0; ks < 2; ++ks) {
            acc[0] = __builtin_amdgcn_mfma_f32_16x16x32_bf16(af[0][ks], bf[ks], acc[0], 0, 0, 0);
            acc[1] = __builtin_amdgcn_mfma_f32_16x16x32_bf16(af[1][ks], bf[ks], acc[1], 0, 0, 0);
        }
        if (it < CC / BK2 - 1) {
            *reinterpret_cast<short8*>(&a_lds[1 - cur][ar][ak])     = areg0;
            *reinterpret_cast<short8*>(&a_lds[1 - cur][ar][ak + 8]) = areg1;
            *reinterpret_cast<short8*>(&b_lds[1 - cur][br][bk])     = breg.v;
        }
        __syncthreads();
    }

    // epilogue: D row = fh*4 + r (o), col = fr (t)
    const int tcol = t0 + wc*16 + fr;
    #pragma unroll
    for (int i = 0; i < 2; ++i) {
        #pragma unroll
        for (int r = 0; r < 4; ++r) {
            const int o = o0 + wr*32 + i*16 + fh*4 + r;
            out[((size_t)b * CC + o) * TT + tcol] = acc[i][r] + bfc[o];
        }
    }
}

extern "C" void kernel_launch(void* const* d_in, const int* in_sizes, int n_in,
                              void* d_out, int out_size, void* d_ws, size_t ws_size,
                              hipStream_t stream) {
    const float* qin  = (const float*)d_in[0];
    const float* kin  = (const float*)d_in[1];
    const float* vin  = (const float*)d_in[2];
    const int*   mask = (const int*)  d_in[3];
    const float* wq   = (const float*)d_in[4];
    const float* wk   = (const float*)d_in[5];
    const float* wv   = (const float*)d_in[6];
    const float* wfc  = (const float*)d_in[7];
    const float* bfc  = (const float*)d_in[8];
    float* out = (float*)d_out;

    __hip_bfloat16* attn  = (__hip_bfloat16*)d_ws;                        // 2 MB
    __hip_bfloat16* wpack = (__hip_bfloat16*)((char*)d_ws + (2u << 20));  // 512 KB

    float* mout = out + (size_t)BB * CC * TT;

    fused_conv_attn_kernel<<<BB * CC + 257, 256, 0, stream>>>(
        qin, kin, vin, mask, wq, wk, wv, wfc, attn, wpack, mout);

    dim3 g(TT / BN2, CC / BM2, BB);   // (32, 8, 2) = 512 blocks
    fc_gemm_kernel<<<g, 256, 0, stream>>>(attn, wpack, bfc, out);
}